// Round 6
// baseline (195.980 us; speedup 1.0000x reference)
//
#include <hip/hip_runtime.h>
#include <hip/hip_bf16.h>

// Problem constants
#define BATCH  128
#define HWN    196          // (224/16)^2 patches per sample
#define HIDN   768
#define KN     768          // 3*16*16
#define IMGSZ  224
#define IMG2   (224*224)
#define MTOT   (BATCH*HWN)  // 25088 rows

// GEMM tiling (round-5 verified glds 2-barrier structure)
#define BM 128
#define BN 128
#define BK 32
#define NT  (KN/BK)         // 24 K-steps
#define NBM (MTOT/BM)       // 196
#define NBN (HIDN/BN)       // 6
#define NWG (NBM*NBN)       // 1176 = 8 * 147 -> bijective XCD swizzle
#define CPX (NWG/8)         // 147

typedef __attribute__((ext_vector_type(8))) short bf16x8;
typedef __attribute__((ext_vector_type(4))) float floatx4;

#define GP(p) ((const __attribute__((address_space(1))) void*)(p))
#define SP(p) ((__attribute__((address_space(3))) void*)(p))

static __device__ __forceinline__ short f2bf(float f) {
    __hip_bfloat16 h = __float2bfloat16(f);   // RNE
    return __builtin_bit_cast(short, h);
}

static __device__ __forceinline__ bf16x8 cvt8v(float4 f0, float4 f1) {
    bf16x8 v;
    v[0]=f2bf(f0.x); v[1]=f2bf(f0.y); v[2]=f2bf(f0.z); v[3]=f2bf(f0.w);
    v[4]=f2bf(f1.x); v[5]=f2bf(f1.y); v[6]=f2bf(f1.z); v[7]=f2bf(f1.w);
    return v;
}

// ---------------------------------------------------------------------------
// prep_W: fp32 -> bf16, 768*768 elems, 8 per thread. 288 blocks of 256.
// ---------------------------------------------------------------------------
__global__ __launch_bounds__(256)
void prep_W(const float* __restrict__ W, unsigned short* __restrict__ Wb)
{
    const int idx = blockIdx.x * 256 + threadIdx.x;   // < 73728
    float4 f0 = *(const float4*)(W + (size_t)idx * 8);
    float4 f1 = *(const float4*)(W + (size_t)idx * 8 + 4);
    *(bf16x8*)(Wb + (size_t)idx * 8) = cvt8v(f0, f1);
}

// ---------------------------------------------------------------------------
// gemm_fused v4: out[gr,n] = sum_k bf16(x[perm-row gr, k]) * Wb[n,k] + bias[n]
// prep_A is ELIMINATED: the A-side global_load_lds reads fp32 straight from x
// (glds source addresses are per-lane -> perm gather + patch addressing fold
// into 4 precomputed per-thread pointers; the per-iteration k-advance is a
// SCALAR offset  off(it) = (it>>3)*IMG2 + (it&7)*448 ).
// A is staged as fp32 [128][32] (16 KB) and converted to bf16 at fragment-
// read time (VALU has 90% headroom). Identical RNE numerics to prep_A.
// LDS slot-XOR: staging thread t holds logical k-slot (t&7)^((t>>3)&7), the
// fragment read applies the same XOR -> linear glds dest + pre-swizzled
// global source + swizzled read (rule #21), A-reads 2-way conflict (free).
// Everything else (2-barrier glds loop, 4x4 acc, XCD-bijective swizzle,
// contiguous epilogue) is the measured-54us round-5 structure.
// ---------------------------------------------------------------------------
__global__ __launch_bounds__(256, 3)
void gemm_fused(const float* __restrict__ x, const int* __restrict__ perm,
                const unsigned short* __restrict__ Wb,
                const float* __restrict__ bias, float* __restrict__ out)
{
    __shared__ __align__(16) float          As[BM * BK];   // 16 KB (fp32!)
    __shared__ __align__(16) unsigned short Bs[BN * BK];   // 8 KB

    const int tid = threadIdx.x;
    const int wg  = blockIdx.x;
    const int lid = (wg & 7) * CPX + (wg >> 3);
    const int bm  = lid / NBN;
    const int bn  = lid - bm * NBN;

    // ---- A staging: 4 glds groups; group g covers rows g*32 + (tid>>3),
    // thread stages 16 B = 4 fp32 of logical k-slot kl = (t&7)^((t>>3)&7).
    const int kl = (tid & 7) ^ ((tid >> 3) & 7);
    const int s2 = kl >> 2;            // which of the 2 iy-rows in a 32-k chunk
    const int k4 = kl & 3;             // 16B piece within the 64B iy-row
    const float* pA0; const float* pA1; const float* pA2; const float* pA3;
#define MKPA(PTR, G)                                                          \
    do {                                                                      \
        const int gr = bm * BM + (G) * 32 + (tid >> 3);                       \
        const int b  = gr / HWN;                                              \
        const int p  = perm[gr];                                              \
        const int py = p / 14, px = p - py * 14;                              \
        PTR = x + (size_t)b * 3 * IMG2 + (size_t)(py * 16 + s2) * IMGSZ       \
                + px * 16 + k4 * 4;                                           \
    } while (0)
    MKPA(pA0, 0); MKPA(pA1, 1); MKPA(pA2, 2); MKPA(pA3, 3);
#undef MKPA

    // ---- B staging map (unchanged round-5): thread stages 16 B of
    // Wb row (tid>>2), k-seg (tid&3).
    const int srow = tid >> 2;
    const int sseg = tid & 3;
    const unsigned short* gb = Wb + (size_t)(bn * BN + srow) * KN + sseg * 8;

    // ---- fragment coords
    const int lane = tid & 63;
    const int wave = tid >> 6;
    const int wm = (wave >> 1) * 64;
    const int wn = (wave & 1) * 64;
    const int lr = lane & 15;
    const int lq = lane >> 4;
    // swizzled A-fragment byte offsets within a 128 B row (row&7 == lr&7
    // since wm and i*16 are multiples of 8):
    const int aoffA = (((lq << 1)    ) ^ (lr & 7)) << 4;
    const int aoffB = (((lq << 1) | 1) ^ (lr & 7)) << 4;

    floatx4 acc[4][4] = {};

    for (int it = 0; it < NT; ++it) {
        // scalar per-iteration source advance (k0 = it*32):
        const int off = (it >> 3) * IMG2 + (it & 7) * 448;
        __builtin_amdgcn_global_load_lds(GP(pA0 + off), SP((char*)As +         tid * 16), 16, 0, 0);
        __builtin_amdgcn_global_load_lds(GP(pA1 + off), SP((char*)As +  4096 + tid * 16), 16, 0, 0);
        __builtin_amdgcn_global_load_lds(GP(pA2 + off), SP((char*)As +  8192 + tid * 16), 16, 0, 0);
        __builtin_amdgcn_global_load_lds(GP(pA3 + off), SP((char*)As + 12288 + tid * 16), 16, 0, 0);
        __builtin_amdgcn_global_load_lds(GP(gb + it * BK),           SP(&Bs[tid * 8]),        16, 0, 0);
        __builtin_amdgcn_global_load_lds(GP(gb + 64 * KN + it * BK), SP(&Bs[2048 + tid * 8]), 16, 0, 0);
        __syncthreads();

        bf16x8 bfrag[4];
        #pragma unroll
        for (int j = 0; j < 4; ++j)
            bfrag[j] = *(const bf16x8*)&Bs[(wn + j * 16 + lr) * BK + lq * 8];
        #pragma unroll
        for (int i = 0; i < 4; ++i) {
            const char* rbase = (const char*)As + (wm + i * 16 + lr) * 128;
            float4 fa = *(const float4*)(rbase + aoffA);
            float4 fb = *(const float4*)(rbase + aoffB);
            const bf16x8 afrag = cvt8v(fa, fb);
            #pragma unroll
            for (int j = 0; j < 4; ++j)
                acc[i][j] = __builtin_amdgcn_mfma_f32_16x16x32_bf16(
                                afrag, bfrag[j], acc[i][j], 0, 0, 0);
        }
        __syncthreads();
    }

    // epilogue: bias + contiguous store (C/D: col = lane&15, row = quad*4+reg)
    #pragma unroll
    for (int j = 0; j < 4; ++j) {
        const int gc = bn * BN + wn + j * 16 + lr;
        const float bv = bias[gc];
        #pragma unroll
        for (int i = 0; i < 4; ++i) {
            const int grow = bm * BM + wm + i * 16 + lq * 4;
            float* op = out + (size_t)grow * HIDN + gc;
            #pragma unroll
            for (int r = 0; r < 4; ++r)
                op[(size_t)r * HIDN] = acc[i][j][r] + bv;
        }
    }
}

extern "C" void kernel_launch(void* const* d_in, const int* in_sizes, int n_in,
                              void* d_out, int out_size, void* d_ws, size_t ws_size,
                              hipStream_t stream) {
    const float* x    = (const float*)d_in[0];
    const float* W    = (const float*)d_in[1];
    const float* bias = (const float*)d_in[2];
    const int*   perm = (const int*)d_in[3];
    float* out = (float*)d_out;

    // workspace: only Wb bf16 [768*768] (1.2 MB) — A never materialized
    unsigned short* Wb = (unsigned short*)d_ws;

    prep_W<<<dim3(KN * HIDN / 8 / 256), dim3(256), 0, stream>>>(W, Wb);
    gemm_fused<<<dim3(NWG), dim3(256), 0, stream>>>(x, perm, Wb, bias, out);
}